// Round 3
// baseline (2041.476 us; speedup 1.0000x reference)
//
#include <hip/hip_runtime.h>

#define NN 50000
#define NE 1600000
#define DD 128
#define NLAYERS 6
#define NG 8
#define BN_EPS 1e-5f

#define NBUCK 391      // ceil(NN / 128)
#define BCAP 5120      // avg 4092/bucket, sigma~64 -> 16-sigma headroom

// ---------------- CSR build: fused hist + bin ----------------

__global__ void k_binhist(const int* __restrict__ src, const int* __restrict__ dst,
                          int* __restrict__ deg, int* __restrict__ bcnt,
                          int2* __restrict__ buf) {
    for (int e = blockIdx.x * blockDim.x + threadIdx.x; e < NE; e += gridDim.x * blockDim.x) {
        int d = dst[e];
        int s = src[e];
        atomicAdd(&deg[d], 1);
        int b = d >> 7;
        int pos = atomicAdd(&bcnt[b], 1);
        if (pos < BCAP) buf[(size_t)b * BCAP + pos] = make_int2(s, d);
    }
}

__global__ __launch_bounds__(1024) void k_scan(const int* __restrict__ deg,
                                               int* __restrict__ off,
                                               int* __restrict__ cur) {
    __shared__ int part[1024];
    int t = threadIdx.x;
    const int CH = (NN + 1023) / 1024;  // 49
    int lo = t * CH, hi = lo + CH; if (hi > NN) hi = NN; if (lo > NN) lo = NN;
    int s = 0;
    for (int i = lo; i < hi; ++i) s += deg[i];
    part[t] = s;
    __syncthreads();
    for (int d = 1; d < 1024; d <<= 1) {
        int v = (t >= d) ? part[t - d] : 0;
        __syncthreads();
        part[t] += v;
        __syncthreads();
    }
    int run = (t == 0) ? 0 : part[t - 1];
    for (int i = lo; i < hi; ++i) {
        off[i] = run; cur[i] = run;
        run += deg[i];
    }
    if (t == 0) off[NN] = NE;
}

__global__ __launch_bounds__(256) void k_bscatter(const int* __restrict__ bcnt,
                                                  const int2* __restrict__ buf,
                                                  int* __restrict__ cur,
                                                  int* __restrict__ csr) {
    int b = blockIdx.x;
    int n = bcnt[b]; if (n > BCAP) n = BCAP;
    for (int i = threadIdx.x; i < n; i += blockDim.x) {
        int2 p = buf[(size_t)b * BCAP + i];
        int pos = atomicAdd(&cur[p.y], 1);
        csr[pos] = p.x;
    }
}

__global__ void k_init_st(float* __restrict__ st) {
    int t = threadIdx.x;
    st[t] = (t < DD) ? 1.f : 0.f;
}

// ---------------- aggregation: one wave per dst node, 2 rows per float4 load ----
// agg'[n][c] = s[c] * sum_{j in N(n)} hraw[j][c] + t[c] * deg(n)

__global__ __launch_bounds__(256) void k_agg(const float* __restrict__ h,
                                             const int* __restrict__ off,
                                             const int* __restrict__ csr,
                                             const float* __restrict__ st,
                                             float* __restrict__ agg) {
    int w = (blockIdx.x * blockDim.x + threadIdx.x) >> 6;
    int lane = threadIdx.x & 63;
    if (w >= NN) return;
    int lo = off[w], hi = off[w + 1];
    const int half = lane >> 5;       // which edge of the pair
    const int colq = lane & 31;       // float4 column quad
    const float4* hp = (const float4*)h;  // row stride 32 float4
    float4 acc = make_float4(0.f, 0.f, 0.f, 0.f);
    int e = lo;
    for (; e + 8 <= hi; e += 8) {
        int s0 = csr[e     + half];
        int s1 = csr[e + 2 + half];
        int s2 = csr[e + 4 + half];
        int s3 = csr[e + 6 + half];
        float4 v0 = hp[(size_t)s0 * 32 + colq];
        float4 v1 = hp[(size_t)s1 * 32 + colq];
        float4 v2 = hp[(size_t)s2 * 32 + colq];
        float4 v3 = hp[(size_t)s3 * 32 + colq];
        acc.x += (v0.x + v1.x) + (v2.x + v3.x);
        acc.y += (v0.y + v1.y) + (v2.y + v3.y);
        acc.z += (v0.z + v1.z) + (v2.z + v3.z);
        acc.w += (v0.w + v1.w) + (v2.w + v3.w);
    }
    for (; e + 2 <= hi; e += 2) {
        int s = csr[e + half];
        float4 v = hp[(size_t)s * 32 + colq];
        acc.x += v.x; acc.y += v.y; acc.z += v.z; acc.w += v.w;
    }
    // combine the two edge-halves: every lane ends with the full sum for its colq
    acc.x += __shfl_xor(acc.x, 32);
    acc.y += __shfl_xor(acc.y, 32);
    acc.z += __shfl_xor(acc.z, 32);
    acc.w += __shfl_xor(acc.w, 32);
    if (e < hi) {  // odd tail edge — add on all lanes (both halves stay equal)
        int s = csr[hi - 1];
        float4 v = hp[(size_t)s * 32 + colq];
        acc.x += v.x; acc.y += v.y; acc.z += v.z; acc.w += v.w;
    }
    float degf = (float)(hi - lo);
    float4 s4 = *(const float4*)(st + colq * 4);
    float4 t4 = *(const float4*)(st + DD + colq * 4);
    float4 o;
    o.x = fmaf(s4.x, acc.x, t4.x * degf);
    o.y = fmaf(s4.y, acc.y, t4.y * degf);
    o.z = fmaf(s4.z, acc.z, t4.z * degf);
    o.w = fmaf(s4.w, acc.w, t4.w * degf);
    if (lane < 32) ((float4*)agg)[(size_t)w * 32 + colq] = o;
}

// ---------------- fused dual GEMM + bias + relu + column stats ----------------
// One block: 64 nodes x all 128 cols. hout = relu(agg' @ Wrel + (s*h+t) @ Wroot + brel)

__global__ __launch_bounds__(256) void k_gemm(const float* __restrict__ agg,
                                              const float* __restrict__ hraw,
                                              const float* __restrict__ st,
                                              const float* __restrict__ Wrel,
                                              const float* __restrict__ Wroot,
                                              const float* __restrict__ brel,
                                              float* __restrict__ hout,
                                              float* __restrict__ stats) {
    __shared__ float As[64][128];
    __shared__ float Bs[64][128];
    const int tid = threadIdx.x;
    const int tx = tid & 31;    // col quad: cols tx*4 .. tx*4+3
    const int ty = tid >> 5;    // row group: rows ty*8 .. ty*8+7
    const int n0 = blockIdx.x * 64;
    float acc[8][4] = {};
    for (int pass = 0; pass < 2; ++pass) {
        const float* A = pass ? hraw : agg;
        const float* W = pass ? Wroot : Wrel;
        if (pass) __syncthreads();  // As reads of pass 0 done
#pragma unroll
        for (int rep = 0; rep < 8; ++rep) {
            int idx = rep * 256 + tid;
            int r = idx >> 5;
            int kq = (idx & 31) * 4;
            int n = n0 + r;
            float4 v = make_float4(0.f, 0.f, 0.f, 0.f);
            if (n < NN) v = *(const float4*)(A + (size_t)n * DD + kq);
            if (pass) {
                float4 s4 = *(const float4*)(st + kq);
                float4 t4 = *(const float4*)(st + DD + kq);
                v.x = fmaf(s4.x, v.x, t4.x);
                v.y = fmaf(s4.y, v.y, t4.y);
                v.z = fmaf(s4.z, v.z, t4.z);
                v.w = fmaf(s4.w, v.w, t4.w);
            }
            *(float4*)(&As[r][kq]) = v;
        }
        for (int kc = 0; kc < DD; kc += 64) {
            __syncthreads();  // As ready / prior Bs reads done
#pragma unroll
            for (int rep = 0; rep < 8; ++rep) {
                int idx = rep * 256 + tid;
                int kl = idx >> 5;
                int j = (idx & 31) * 4;
                *(float4*)(&Bs[kl][j]) = *(const float4*)(W + (size_t)(kc + kl) * DD + j);
            }
            __syncthreads();
#pragma unroll
            for (int k4 = 0; k4 < 64; k4 += 4) {
                float4 a4[8];
#pragma unroll
                for (int i = 0; i < 8; ++i)
                    a4[i] = *(const float4*)(&As[ty * 8 + i][kc + k4]);
#pragma unroll
                for (int q = 0; q < 4; ++q) {
                    float4 b = *(const float4*)(&Bs[k4 + q][tx * 4]);
#pragma unroll
                    for (int i = 0; i < 8; ++i) {
                        float a = (q == 0) ? a4[i].x : (q == 1) ? a4[i].y : (q == 2) ? a4[i].z : a4[i].w;
                        acc[i][0] = fmaf(a, b.x, acc[i][0]);
                        acc[i][1] = fmaf(a, b.y, acc[i][1]);
                        acc[i][2] = fmaf(a, b.z, acc[i][2]);
                        acc[i][3] = fmaf(a, b.w, acc[i][3]);
                    }
                }
            }
        }
    }
    float4 bias = *(const float4*)(brel + tx * 4);
    float csum[4] = {0.f, 0.f, 0.f, 0.f};
    float csq[4] = {0.f, 0.f, 0.f, 0.f};
#pragma unroll
    for (int i = 0; i < 8; ++i) {
        int n = n0 + ty * 8 + i;
        if (n < NN) {
            float4 o;
            o.x = fmaxf(acc[i][0] + bias.x, 0.f);
            o.y = fmaxf(acc[i][1] + bias.y, 0.f);
            o.z = fmaxf(acc[i][2] + bias.z, 0.f);
            o.w = fmaxf(acc[i][3] + bias.w, 0.f);
            *(float4*)(hout + (size_t)n * DD + tx * 4) = o;
            csum[0] += o.x; csum[1] += o.y; csum[2] += o.z; csum[3] += o.w;
            csq[0] += o.x * o.x; csq[1] += o.y * o.y;
            csq[2] += o.z * o.z; csq[3] += o.w * o.w;
        }
    }
    __syncthreads();  // done reading As/Bs
    *(float4*)(&As[ty][tx * 4]) = make_float4(csum[0], csum[1], csum[2], csum[3]);
    *(float4*)(&As[8 + ty][tx * 4]) = make_float4(csq[0], csq[1], csq[2], csq[3]);
    __syncthreads();
    if (tid < 256) {
        int isq = tid >> 7;      // 0 = sum, 1 = sumsq
        int cc = tid & 127;
        float s = 0.f;
#pragma unroll
        for (int r = 0; r < 8; ++r) s += As[isq * 8 + r][cc];
        atomicAdd(&stats[isq * DD + cc], s);
    }
}

__global__ void k_bn(float* __restrict__ stats, const float* __restrict__ gamma,
                     const float* __restrict__ beta, float* __restrict__ st) {
    int c = threadIdx.x;  // 128 threads
    float mean = stats[c] * (1.0f / NN);
    float var = stats[DD + c] * (1.0f / NN) - mean * mean;
    float s = gamma[c] / sqrtf(var + BN_EPS);
    st[c] = s;
    st[DD + c] = beta[c] - mean * s;
    stats[c] = 0.f;
    stats[DD + c] = 0.f;
}

// ---------------- pooling: contiguous chunks, flush on graph change ----------------

#define POOL_BLOCKS 128

__global__ __launch_bounds__(256) void k_pool(const float* __restrict__ h,
                                              const int* __restrict__ batch,
                                              float* __restrict__ pooled,
                                              float* __restrict__ counts) {
    const int c = threadIdx.x & 127;
    const int half = threadIdx.x >> 7;
    const int chunk = (NN + POOL_BLOCKS - 1) / POOL_BLOCKS;
    int lo = blockIdx.x * chunk;
    int hi = lo + chunk; if (hi > NN) hi = NN;
    float acc = 0.f;
    int cur = -1, cnt = 0;
    for (int n = lo + half; n < hi; n += 2) {
        int g = batch[n];
        float v = h[(size_t)n * DD + c];
        if (g != cur) {
            if (cur >= 0) {
                atomicAdd(&pooled[cur * DD + c], acc);
                if (c == 0) atomicAdd(&counts[cur], (float)cnt);
            }
            cur = g; acc = 0.f; cnt = 0;
        }
        acc += v; cnt++;
    }
    if (cur >= 0) {
        atomicAdd(&pooled[cur * DD + c], acc);
        if (c == 0) atomicAdd(&counts[cur], (float)cnt);
    }
}

// ---------------- head ----------------

__global__ __launch_bounds__(1024) void k_head(const float* __restrict__ pooled,
                                               const float* __restrict__ counts,
                                               const float* __restrict__ st,
                                               const float* __restrict__ dw,
                                               const float* __restrict__ db,
                                               const float* __restrict__ muw,
                                               const float* __restrict__ mub,
                                               float* __restrict__ out) {
    __shared__ float pm[NG][DD];
    __shared__ float zs[NG][DD];
    int t = threadIdx.x;
    int g = t >> 7, c = t & 127;
    float cntg = counts[g];
    pm[g][c] = fmaf(st[c], pooled[g * DD + c], st[DD + c] * cntg) / fmaxf(cntg, 1.0f);
    __syncthreads();
    float acc = 0.f;
    for (int k = 0; k < DD; ++k)
        acc = fmaf(pm[g][k], dw[k * DD + c], acc);
    float z = fmaxf(acc + db[c], 0.f);
    zs[g][c] = z * muw[c];
    __syncthreads();
    if (c == 0) {
        float s = 0.f;
        for (int k = 0; k < DD; ++k) s += zs[g][k];
        out[g] = s + mub[0];
    }
}

// ---------------- host ----------------

extern "C" void kernel_launch(void* const* d_in, const int* in_sizes, int n_in,
                              void* d_out, int out_size, void* d_ws, size_t ws_size,
                              hipStream_t stream) {
    const float* x      = (const float*)d_in[0];
    const int*   ei     = (const int*)d_in[1];
    const int*   batch  = (const int*)d_in[2];
    const float* W_rel  = (const float*)d_in[3];
    const float* b_rel  = (const float*)d_in[4];
    const float* W_root = (const float*)d_in[5];
    const float* gamma  = (const float*)d_in[6];
    const float* beta   = (const float*)d_in[7];
    const float* dw     = (const float*)d_in[8];
    const float* db     = (const float*)d_in[9];
    const float* muw    = (const float*)d_in[10];
    const float* mub    = (const float*)d_in[11];
    float* out = (float*)d_out;

    char* w = (char*)d_ws;
    auto alloc = [&](size_t bytes) {
        char* p = w;
        w += (bytes + 255) & ~(size_t)255;
        return p;
    };
    int*   deg    = (int*)alloc((size_t)NN * 4);
    int*   off    = (int*)alloc((size_t)(NN + 1) * 4);
    int*   cur    = (int*)alloc((size_t)NN * 4);
    int*   csr    = (int*)alloc((size_t)NE * 4);
    float* hA     = (float*)alloc((size_t)NN * DD * 4);
    float* hB     = (float*)alloc((size_t)NN * DD * 4);
    float* aggb   = (float*)alloc((size_t)NN * DD * 4);  // also bucket buf pre-layers
    float* stats  = (float*)alloc(2 * DD * 4);
    float* st     = (float*)alloc(2 * DD * 4);
    float* pooled = (float*)alloc(NG * DD * 4);
    float* counts = (float*)alloc(NG * 4);
    int*   bcnt   = (int*)alloc((size_t)NBUCK * 4);

    const int* src = ei;
    const int* dst = ei + NE;
    int2* bbuf = (int2*)aggb;  // NBUCK*BCAP*8 = 16.0 MB <= 25.6 MB

    hipMemsetAsync(deg, 0, (size_t)NN * 4, stream);
    hipMemsetAsync(bcnt, 0, (size_t)NBUCK * 4, stream);
    hipMemsetAsync(stats, 0, 2 * DD * 4, stream);
    k_binhist<<<2048, 256, 0, stream>>>(src, dst, deg, bcnt, bbuf);
    k_scan<<<1, 1024, 0, stream>>>(deg, off, cur);
    k_bscatter<<<NBUCK, 256, 0, stream>>>(bcnt, bbuf, cur, csr);
    k_init_st<<<1, 256, 0, stream>>>(st);

    const float* hcur = x;
    float* bufs[2] = {hA, hB};
    for (int i = 0; i < NLAYERS; ++i) {
        float* hnext = bufs[i & 1];
        k_agg<<<(NN * 64 + 255) / 256, 256, 0, stream>>>(hcur, off, csr, st, aggb);
        k_gemm<<<(NN + 63) / 64, 256, 0, stream>>>(
            aggb, hcur, st, W_rel + (size_t)i * DD * DD, W_root + (size_t)i * DD * DD,
            b_rel + (size_t)i * DD, hnext, stats);
        k_bn<<<1, 128, 0, stream>>>(stats, gamma + (size_t)i * DD, beta + (size_t)i * DD, st);
        hcur = hnext;
    }
    hipMemsetAsync(pooled, 0, (size_t)NG * DD * 4, stream);
    hipMemsetAsync(counts, 0, (size_t)NG * 4, stream);
    k_pool<<<POOL_BLOCKS, 256, 0, stream>>>(hcur, batch, pooled, counts);
    k_head<<<1, 1024, 0, stream>>>(pooled, counts, st, dw, db, muw, mub, out);
}

// Round 4
// 1579.582 us; speedup vs baseline: 1.2924x; 1.2924x over previous
//
#include <hip/hip_runtime.h>

#define NN 50000
#define NE 1600000
#define DD 128
#define NLAYERS 6
#define NG 8
#define BN_EPS 1e-5f

// ---------------- CSR build (R2-proven path) ----------------

__global__ void k_hist(const int* __restrict__ dst, int* __restrict__ deg) {
    for (int e = blockIdx.x * blockDim.x + threadIdx.x; e < NE; e += gridDim.x * blockDim.x)
        atomicAdd(&deg[dst[e]], 1);
}

__global__ __launch_bounds__(1024) void k_scan(const int* __restrict__ deg,
                                               int* __restrict__ off,
                                               int* __restrict__ cur) {
    __shared__ int part[1024];
    int t = threadIdx.x;
    const int CH = (NN + 1023) / 1024;  // 49
    int lo = t * CH, hi = lo + CH; if (hi > NN) hi = NN; if (lo > NN) lo = NN;
    int s = 0;
    for (int i = lo; i < hi; ++i) s += deg[i];
    part[t] = s;
    __syncthreads();
    for (int d = 1; d < 1024; d <<= 1) {
        int v = (t >= d) ? part[t - d] : 0;
        __syncthreads();
        part[t] += v;
        __syncthreads();
    }
    int run = (t == 0) ? 0 : part[t - 1];
    for (int i = lo; i < hi; ++i) {
        off[i] = run; cur[i] = run;
        run += deg[i];
    }
    if (t == 0) off[NN] = NE;
}

__global__ void k_scatter(const int* __restrict__ src, const int* __restrict__ dst,
                          int* __restrict__ cur, int* __restrict__ csr) {
    for (int e = blockIdx.x * blockDim.x + threadIdx.x; e < NE; e += gridDim.x * blockDim.x) {
        int d = dst[e];
        int p = atomicAdd(&cur[d], 1);
        csr[p] = src[e];
    }
}

__global__ void k_init_st(float* __restrict__ st) {
    int t = threadIdx.x;
    st[t] = (t < DD) ? 1.f : 0.f;
}

// ---------------- fused layer: gather-agg + dual GEMM + bias + relu + stats ----
// Block = 64 nodes x 128 cols. LDS 48KB -> 3 blocks/CU so gather-phase blocks
// overlap with GEMM-phase blocks on the same CU (mem pipe || VALU pipe).

__global__ __launch_bounds__(256) void k_layer(const float* __restrict__ h,
                                               const int* __restrict__ off,
                                               const int* __restrict__ csr,
                                               const float* __restrict__ st,
                                               const float* __restrict__ Wrel,
                                               const float* __restrict__ Wroot,
                                               const float* __restrict__ brel,
                                               float* __restrict__ hout,
                                               float* __restrict__ stats) {
    __shared__ float As[64][128];
    __shared__ float Bs[32][128];
    const int tid = threadIdx.x;
    const int n0 = blockIdx.x * 64;

    // ---- Phase G: aggregate 16 nodes per wave into As (BN-scaled) ----
    {
        const int wv = tid >> 6;
        const int lane = tid & 63;
        const int half = lane >> 5;
        const int colq = lane & 31;
        const float4* hp = (const float4*)h;  // row stride = 32 float4
        float4 s4 = *(const float4*)(st + colq * 4);
        float4 t4 = *(const float4*)(st + DD + colq * 4);
        for (int r = wv * 16; r < wv * 16 + 16; ++r) {
            int w = n0 + r;
            float4 acc = make_float4(0.f, 0.f, 0.f, 0.f);
            float degf = 0.f;
            if (w < NN) {
                int lo = off[w], hi = off[w + 1];
                degf = (float)(hi - lo);
                int e = lo;
                for (; e + 8 <= hi; e += 8) {
                    int s0 = csr[e     + half];
                    int s1 = csr[e + 2 + half];
                    int s2 = csr[e + 4 + half];
                    int s3 = csr[e + 6 + half];
                    float4 v0 = hp[(size_t)s0 * 32 + colq];
                    float4 v1 = hp[(size_t)s1 * 32 + colq];
                    float4 v2 = hp[(size_t)s2 * 32 + colq];
                    float4 v3 = hp[(size_t)s3 * 32 + colq];
                    acc.x += (v0.x + v1.x) + (v2.x + v3.x);
                    acc.y += (v0.y + v1.y) + (v2.y + v3.y);
                    acc.z += (v0.z + v1.z) + (v2.z + v3.z);
                    acc.w += (v0.w + v1.w) + (v2.w + v3.w);
                }
                for (; e + 2 <= hi; e += 2) {
                    int s = csr[e + half];
                    float4 v = hp[(size_t)s * 32 + colq];
                    acc.x += v.x; acc.y += v.y; acc.z += v.z; acc.w += v.w;
                }
                acc.x += __shfl_xor(acc.x, 32);
                acc.y += __shfl_xor(acc.y, 32);
                acc.z += __shfl_xor(acc.z, 32);
                acc.w += __shfl_xor(acc.w, 32);
                if (e < hi) {  // odd tail edge: add on all lanes (halves stay equal)
                    int s = csr[hi - 1];
                    float4 v = hp[(size_t)s * 32 + colq];
                    acc.x += v.x; acc.y += v.y; acc.z += v.z; acc.w += v.w;
                }
            }
            if (lane < 32) {
                float4 o;
                o.x = fmaf(s4.x, acc.x, t4.x * degf);
                o.y = fmaf(s4.y, acc.y, t4.y * degf);
                o.z = fmaf(s4.z, acc.z, t4.z * degf);
                o.w = fmaf(s4.w, acc.w, t4.w * degf);
                *(float4*)(&As[r][colq * 4]) = o;
            }
        }
    }

    // ---- dual GEMM ----
    const int tx = tid & 31;    // col quad
    const int ty = tid >> 5;    // row group of 8
    float acc[8][4] = {};
    for (int pass = 0; pass < 2; ++pass) {
        const float* W = pass ? Wroot : Wrel;
        if (pass) {
            __syncthreads();  // pass-0 As/Bs reads done before As overwrite
#pragma unroll
            for (int rep = 0; rep < 8; ++rep) {
                int idx = rep * 256 + tid;
                int r = idx >> 5;
                int kq = (idx & 31) * 4;
                int n = n0 + r;
                float4 v = make_float4(0.f, 0.f, 0.f, 0.f);
                if (n < NN) v = *(const float4*)(h + (size_t)n * DD + kq);
                float4 s4 = *(const float4*)(st + kq);
                float4 t4 = *(const float4*)(st + DD + kq);
                v.x = fmaf(s4.x, v.x, t4.x);
                v.y = fmaf(s4.y, v.y, t4.y);
                v.z = fmaf(s4.z, v.z, t4.z);
                v.w = fmaf(s4.w, v.w, t4.w);
                *(float4*)(&As[r][kq]) = v;
            }
        }
        for (int kc = 0; kc < DD; kc += 32) {
            __syncthreads();  // As ready / prior Bs reads done
#pragma unroll
            for (int rep = 0; rep < 4; ++rep) {
                int idx = rep * 256 + tid;
                int kl = idx >> 5;
                int j = (idx & 31) * 4;
                *(float4*)(&Bs[kl][j]) = *(const float4*)(W + (size_t)(kc + kl) * DD + j);
            }
            __syncthreads();
#pragma unroll
            for (int k4 = 0; k4 < 32; k4 += 4) {
                float4 a4[8];
#pragma unroll
                for (int i = 0; i < 8; ++i)
                    a4[i] = *(const float4*)(&As[ty * 8 + i][kc + k4]);
#pragma unroll
                for (int q = 0; q < 4; ++q) {
                    float4 b = *(const float4*)(&Bs[k4 + q][tx * 4]);
#pragma unroll
                    for (int i = 0; i < 8; ++i) {
                        float a = (q == 0) ? a4[i].x : (q == 1) ? a4[i].y : (q == 2) ? a4[i].z : a4[i].w;
                        acc[i][0] = fmaf(a, b.x, acc[i][0]);
                        acc[i][1] = fmaf(a, b.y, acc[i][1]);
                        acc[i][2] = fmaf(a, b.z, acc[i][2]);
                        acc[i][3] = fmaf(a, b.w, acc[i][3]);
                    }
                }
            }
        }
    }

    // ---- epilogue: bias + relu + store + column stats ----
    float4 bias = *(const float4*)(brel + tx * 4);
    float csum[4] = {0.f, 0.f, 0.f, 0.f};
    float csq[4] = {0.f, 0.f, 0.f, 0.f};
#pragma unroll
    for (int i = 0; i < 8; ++i) {
        int n = n0 + ty * 8 + i;
        if (n < NN) {
            float4 o;
            o.x = fmaxf(acc[i][0] + bias.x, 0.f);
            o.y = fmaxf(acc[i][1] + bias.y, 0.f);
            o.z = fmaxf(acc[i][2] + bias.z, 0.f);
            o.w = fmaxf(acc[i][3] + bias.w, 0.f);
            *(float4*)(hout + (size_t)n * DD + tx * 4) = o;
            csum[0] += o.x; csum[1] += o.y; csum[2] += o.z; csum[3] += o.w;
            csq[0] += o.x * o.x; csq[1] += o.y * o.y;
            csq[2] += o.z * o.z; csq[3] += o.w * o.w;
        }
    }
    __syncthreads();  // done reading As/Bs
    *(float4*)(&As[ty][tx * 4]) = make_float4(csum[0], csum[1], csum[2], csum[3]);
    *(float4*)(&As[8 + ty][tx * 4]) = make_float4(csq[0], csq[1], csq[2], csq[3]);
    __syncthreads();
    {
        int isq = tid >> 7;      // 0 = sum, 1 = sumsq
        int cc = tid & 127;
        float s = 0.f;
#pragma unroll
        for (int r = 0; r < 8; ++r) s += As[isq * 8 + r][cc];
        atomicAdd(&stats[isq * DD + cc], s);
    }
}

__global__ void k_bn(float* __restrict__ stats, const float* __restrict__ gamma,
                     const float* __restrict__ beta, float* __restrict__ st) {
    int c = threadIdx.x;  // 128 threads
    float mean = stats[c] * (1.0f / NN);
    float var = stats[DD + c] * (1.0f / NN) - mean * mean;
    float s = gamma[c] / sqrtf(var + BN_EPS);
    st[c] = s;
    st[DD + c] = beta[c] - mean * s;
    stats[c] = 0.f;
    stats[DD + c] = 0.f;
}

// ---------------- pooling: contiguous chunks, flush on graph change ----------------

#define POOL_BLOCKS 128

__global__ __launch_bounds__(256) void k_pool(const float* __restrict__ h,
                                              const int* __restrict__ batch,
                                              float* __restrict__ pooled,
                                              float* __restrict__ counts) {
    const int c = threadIdx.x & 127;
    const int half = threadIdx.x >> 7;
    const int chunk = (NN + POOL_BLOCKS - 1) / POOL_BLOCKS;
    int lo = blockIdx.x * chunk;
    int hi = lo + chunk; if (hi > NN) hi = NN;
    float acc = 0.f;
    int cur = -1, cnt = 0;
    for (int n = lo + half; n < hi; n += 2) {
        int g = batch[n];
        float v = h[(size_t)n * DD + c];
        if (g != cur) {
            if (cur >= 0) {
                atomicAdd(&pooled[cur * DD + c], acc);
                if (c == 0) atomicAdd(&counts[cur], (float)cnt);
            }
            cur = g; acc = 0.f; cnt = 0;
        }
        acc += v; cnt++;
    }
    if (cur >= 0) {
        atomicAdd(&pooled[cur * DD + c], acc);
        if (c == 0) atomicAdd(&counts[cur], (float)cnt);
    }
}

// ---------------- head ----------------

__global__ __launch_bounds__(1024) void k_head(const float* __restrict__ pooled,
                                               const float* __restrict__ counts,
                                               const float* __restrict__ st,
                                               const float* __restrict__ dw,
                                               const float* __restrict__ db,
                                               const float* __restrict__ muw,
                                               const float* __restrict__ mub,
                                               float* __restrict__ out) {
    __shared__ float pm[NG][DD];
    __shared__ float zs[NG][DD];
    int t = threadIdx.x;
    int g = t >> 7, c = t & 127;
    float cntg = counts[g];
    pm[g][c] = fmaf(st[c], pooled[g * DD + c], st[DD + c] * cntg) / fmaxf(cntg, 1.0f);
    __syncthreads();
    float acc = 0.f;
    for (int k = 0; k < DD; ++k)
        acc = fmaf(pm[g][k], dw[k * DD + c], acc);
    float z = fmaxf(acc + db[c], 0.f);
    zs[g][c] = z * muw[c];
    __syncthreads();
    if (c == 0) {
        float s = 0.f;
        for (int k = 0; k < DD; ++k) s += zs[g][k];
        out[g] = s + mub[0];
    }
}

// ---------------- host ----------------

extern "C" void kernel_launch(void* const* d_in, const int* in_sizes, int n_in,
                              void* d_out, int out_size, void* d_ws, size_t ws_size,
                              hipStream_t stream) {
    const float* x      = (const float*)d_in[0];
    const int*   ei     = (const int*)d_in[1];
    const int*   batch  = (const int*)d_in[2];
    const float* W_rel  = (const float*)d_in[3];
    const float* b_rel  = (const float*)d_in[4];
    const float* W_root = (const float*)d_in[5];
    const float* gamma  = (const float*)d_in[6];
    const float* beta   = (const float*)d_in[7];
    const float* dw     = (const float*)d_in[8];
    const float* db     = (const float*)d_in[9];
    const float* muw    = (const float*)d_in[10];
    const float* mub    = (const float*)d_in[11];
    float* out = (float*)d_out;

    char* w = (char*)d_ws;
    auto alloc = [&](size_t bytes) {
        char* p = w;
        w += (bytes + 255) & ~(size_t)255;
        return p;
    };
    int*   deg    = (int*)alloc((size_t)NN * 4);
    int*   off    = (int*)alloc((size_t)(NN + 1) * 4);
    int*   cur    = (int*)alloc((size_t)NN * 4);
    int*   csr    = (int*)alloc((size_t)NE * 4);
    float* hA     = (float*)alloc((size_t)NN * DD * 4);
    float* hB     = (float*)alloc((size_t)NN * DD * 4);
    float* stats  = (float*)alloc(2 * DD * 4);
    float* st     = (float*)alloc(2 * DD * 4);
    float* pooled = (float*)alloc(NG * DD * 4);
    float* counts = (float*)alloc(NG * 4);

    const int* src = ei;
    const int* dst = ei + NE;

    hipMemsetAsync(deg, 0, (size_t)NN * 4, stream);
    hipMemsetAsync(stats, 0, 2 * DD * 4, stream);
    k_hist<<<2048, 256, 0, stream>>>(dst, deg);
    k_scan<<<1, 1024, 0, stream>>>(deg, off, cur);
    k_scatter<<<2048, 256, 0, stream>>>(src, dst, cur, csr);
    k_init_st<<<1, 256, 0, stream>>>(st);

    const float* hcur = x;
    float* bufs[2] = {hA, hB};
    for (int i = 0; i < NLAYERS; ++i) {
        float* hnext = bufs[i & 1];
        k_layer<<<(NN + 63) / 64, 256, 0, stream>>>(
            hcur, off, csr, st, W_rel + (size_t)i * DD * DD, W_root + (size_t)i * DD * DD,
            b_rel + (size_t)i * DD, hnext, stats);
        k_bn<<<1, 128, 0, stream>>>(stats, gamma + (size_t)i * DD, beta + (size_t)i * DD, st);
        hcur = hnext;
    }
    hipMemsetAsync(pooled, 0, (size_t)NG * DD * 4, stream);
    hipMemsetAsync(counts, 0, (size_t)NG * 4, stream);
    k_pool<<<POOL_BLOCKS, 256, 0, stream>>>(hcur, batch, pooled, counts);
    k_head<<<1, 1024, 0, stream>>>(pooled, counts, st, dw, db, muw, mub, out);
}

// Round 5
// 1269.274 us; speedup vs baseline: 1.6084x; 1.2445x over previous
//
#include <hip/hip_runtime.h>

#define NN 50000
#define NE 1600000
#define DD 128
#define NLAYERS 6
#define NG 8
#define BN_EPS 1e-5f

typedef __bf16 bf16x8 __attribute__((ext_vector_type(8)));
typedef float f32x4 __attribute__((ext_vector_type(4)));

// ---------------- CSR build (R2-proven path) ----------------

__global__ void k_hist(const int* __restrict__ dst, int* __restrict__ deg) {
    for (int e = blockIdx.x * blockDim.x + threadIdx.x; e < NE; e += gridDim.x * blockDim.x)
        atomicAdd(&deg[dst[e]], 1);
}

__global__ __launch_bounds__(1024) void k_scan(const int* __restrict__ deg,
                                               int* __restrict__ off,
                                               int* __restrict__ cur) {
    __shared__ int part[1024];
    int t = threadIdx.x;
    const int CH = (NN + 1023) / 1024;  // 49
    int lo = t * CH, hi = lo + CH; if (hi > NN) hi = NN; if (lo > NN) lo = NN;
    int s = 0;
    for (int i = lo; i < hi; ++i) s += deg[i];
    part[t] = s;
    __syncthreads();
    for (int d = 1; d < 1024; d <<= 1) {
        int v = (t >= d) ? part[t - d] : 0;
        __syncthreads();
        part[t] += v;
        __syncthreads();
    }
    int run = (t == 0) ? 0 : part[t - 1];
    for (int i = lo; i < hi; ++i) {
        off[i] = run; cur[i] = run;
        run += deg[i];
    }
    if (t == 0) off[NN] = NE;
}

__global__ void k_scatter(const int* __restrict__ src, const int* __restrict__ dst,
                          int* __restrict__ cur, int* __restrict__ csr) {
    for (int e = blockIdx.x * blockDim.x + threadIdx.x; e < NE; e += gridDim.x * blockDim.x) {
        int d = dst[e];
        int p = atomicAdd(&cur[d], 1);
        csr[p] = src[e];
    }
}

__global__ void k_init_st(float* __restrict__ st) {
    int t = threadIdx.x;
    st[t] = (t < DD) ? 1.f : 0.f;
}

// ---------------- weight prep: f32 [k][n] -> packed bf16 hi/lo transposed [n][k] ----

__global__ __launch_bounds__(256) void k_wprep(const float* __restrict__ Wrel,
                                               const float* __restrict__ Wroot,
                                               __bf16* __restrict__ wbuf) {
    int g = blockIdx.x * 256 + threadIdx.x;   // 24576 tasks
    int li = g >> 11;                          // layer*2 + input
    int rest = g & 2047;
    int k8 = rest >> 7;
    int n = rest & 127;
    int layer = li >> 1, input = li & 1;
    const float* src = (input ? Wroot : Wrel) + (size_t)layer * DD * DD;
    bf16x8 vh, vl;
#pragma unroll
    for (int j = 0; j < 8; ++j) {
        float v = src[(size_t)(k8 * 8 + j) * DD + n];
        __bf16 hb = (__bf16)v;
        vh[j] = hb;
        vl[j] = (__bf16)(v - (float)hb);
    }
    __bf16* dh = wbuf + (size_t)li * 32768 + n * DD + k8 * 8;
    *(bf16x8*)dh = vh;
    *(bf16x8*)(dh + 16384) = vl;
}

// ---------------- aggregation: one wave per dst node (R2-proven) ----------------

__global__ __launch_bounds__(256) void k_agg(const float* __restrict__ h,
                                             const int* __restrict__ off,
                                             const int* __restrict__ csr,
                                             const float* __restrict__ st,
                                             float* __restrict__ agg) {
    int w = (blockIdx.x * blockDim.x + threadIdx.x) >> 6;
    int lane = threadIdx.x & 63;
    if (w >= NN) return;
    int lo = off[w], hi = off[w + 1];
    const int half = lane >> 5;
    const int colq = lane & 31;
    const float4* hp = (const float4*)h;
    float4 acc = make_float4(0.f, 0.f, 0.f, 0.f);
    int e = lo;
    for (; e + 8 <= hi; e += 8) {
        int s0 = csr[e     + half];
        int s1 = csr[e + 2 + half];
        int s2 = csr[e + 4 + half];
        int s3 = csr[e + 6 + half];
        float4 v0 = hp[(size_t)s0 * 32 + colq];
        float4 v1 = hp[(size_t)s1 * 32 + colq];
        float4 v2 = hp[(size_t)s2 * 32 + colq];
        float4 v3 = hp[(size_t)s3 * 32 + colq];
        acc.x += (v0.x + v1.x) + (v2.x + v3.x);
        acc.y += (v0.y + v1.y) + (v2.y + v3.y);
        acc.z += (v0.z + v1.z) + (v2.z + v3.z);
        acc.w += (v0.w + v1.w) + (v2.w + v3.w);
    }
    for (; e + 2 <= hi; e += 2) {
        int s = csr[e + half];
        float4 v = hp[(size_t)s * 32 + colq];
        acc.x += v.x; acc.y += v.y; acc.z += v.z; acc.w += v.w;
    }
    acc.x += __shfl_xor(acc.x, 32);
    acc.y += __shfl_xor(acc.y, 32);
    acc.z += __shfl_xor(acc.z, 32);
    acc.w += __shfl_xor(acc.w, 32);
    if (e < hi) {
        int s = csr[hi - 1];
        float4 v = hp[(size_t)s * 32 + colq];
        acc.x += v.x; acc.y += v.y; acc.z += v.z; acc.w += v.w;
    }
    float degf = (float)(hi - lo);
    float4 s4 = *(const float4*)(st + colq * 4);
    float4 t4 = *(const float4*)(st + DD + colq * 4);
    float4 o;
    o.x = fmaf(s4.x, acc.x, t4.x * degf);
    o.y = fmaf(s4.y, acc.y, t4.y * degf);
    o.z = fmaf(s4.z, acc.z, t4.z * degf);
    o.w = fmaf(s4.w, acc.w, t4.w * degf);
    if (lane < 32) ((float4*)agg)[(size_t)w * 32 + colq] = o;
}

// ---------------- MFMA GEMM (split-bf16 x3) + bias + relu + stats ----------------
// Block = 64 rows x 128 cols, 4 waves; wave w -> rows [w*16, w*16+16).
// D = (Ahi+Alo)(Bhi+Blo) ~= Ahi*Bhi + Alo*Bhi + Ahi*Blo  (lo*lo ~ 2^-18, dropped)

__global__ __launch_bounds__(256) void k_gemm(const float* __restrict__ agg,
                                              const float* __restrict__ hraw,
                                              const float* __restrict__ st,
                                              const __bf16* __restrict__ wrel_pk,
                                              const __bf16* __restrict__ wroot_pk,
                                              const float* __restrict__ brel,
                                              float* __restrict__ hout,
                                              float* __restrict__ stats) {
    __shared__ __align__(16) __bf16 A_hi[64 * 128];
    __shared__ __align__(16) __bf16 A_lo[64 * 128];
    __shared__ __align__(16) __bf16 Bt_hi[128 * 64];
    __shared__ __align__(16) __bf16 Bt_lo[128 * 64];
    const int tid = threadIdx.x;
    const int n0 = blockIdx.x * 64;
    const int w = tid >> 6, lane = tid & 63;
    const int lrow = lane & 15, lk = lane >> 4;
    const int arow = w * 16 + lrow;

    f32x4 acc[8];
#pragma unroll
    for (int ct = 0; ct < 8; ++ct) acc[ct] = (f32x4){0.f, 0.f, 0.f, 0.f};

    for (int p = 0; p < 2; ++p) {
        const float* Asrc = p ? hraw : agg;
        const __bf16* wb = p ? wroot_pk : wrel_pk;
        __syncthreads();  // prior A-frag reads done
        // ---- stage A (64 rows x full K=128) as hi/lo bf16, XOR-swizzled chunks ----
#pragma unroll
        for (int rep = 0; rep < 4; ++rep) {
            int idx = rep * 256 + tid;
            int r = idx >> 4, chunk = idx & 15;
            int n = n0 + r;
            float v[8];
            if (n < NN) {
                float4 a = *(const float4*)(Asrc + (size_t)n * DD + chunk * 8);
                float4 b = *(const float4*)(Asrc + (size_t)n * DD + chunk * 8 + 4);
                v[0] = a.x; v[1] = a.y; v[2] = a.z; v[3] = a.w;
                v[4] = b.x; v[5] = b.y; v[6] = b.z; v[7] = b.w;
                if (p) {
#pragma unroll
                    for (int j = 0; j < 8; ++j) {
                        int k = chunk * 8 + j;
                        v[j] = fmaf(st[k], v[j], st[DD + k]);
                    }
                }
            } else {
#pragma unroll
                for (int j = 0; j < 8; ++j) v[j] = 0.f;
            }
            bf16x8 vh, vl;
#pragma unroll
            for (int j = 0; j < 8; ++j) {
                __bf16 hb = (__bf16)v[j];
                vh[j] = hb;
                vl[j] = (__bf16)(v[j] - (float)hb);
            }
            int eo = r * 128 + ((chunk ^ (r & 7)) << 3);
            *(bf16x8*)(A_hi + eo) = vh;
            *(bf16x8*)(A_lo + eo) = vl;
        }
        for (int kh = 0; kh < 2; ++kh) {
            __syncthreads();  // A ready / prior Bt reads done
            // ---- stage Bt (128 cols x 64 k) hi+lo from packed weights ----
#pragma unroll
            for (int rep = 0; rep < 8; ++rep) {
                int idx = rep * 256 + tid;     // 0..2047
                int halfsel = idx >> 10;       // 0 = hi, 1 = lo
                int t2 = idx & 1023;
                int c = t2 >> 3, chunk = t2 & 7;
                const uint4* srcp = (const uint4*)(wb + halfsel * 16384 + c * DD + kh * 64 + chunk * 8);
                __bf16* dstp = (halfsel ? Bt_lo : Bt_hi) + c * 64 + ((chunk ^ (c & 7)) << 3);
                *(uint4*)dstp = *srcp;
            }
            __syncthreads();  // B ready
#pragma unroll
            for (int ks = 0; ks < 2; ++ks) {
                int ks_g = kh * 2 + ks;
                int chA = ks_g * 4 + lk;
                int eoA = arow * 128 + ((chA ^ (arow & 7)) << 3);
                bf16x8 ah = *(const bf16x8*)(A_hi + eoA);
                bf16x8 al = *(const bf16x8*)(A_lo + eoA);
#pragma unroll
                for (int ct = 0; ct < 8; ++ct) {
                    int c = ct * 16 + lrow;
                    int chB = ks * 4 + lk;
                    int eoB = c * 64 + ((chB ^ (c & 7)) << 3);
                    bf16x8 bh = *(const bf16x8*)(Bt_hi + eoB);
                    bf16x8 bl = *(const bf16x8*)(Bt_lo + eoB);
                    acc[ct] = __builtin_amdgcn_mfma_f32_16x16x32_bf16(ah, bh, acc[ct], 0, 0, 0);
                    acc[ct] = __builtin_amdgcn_mfma_f32_16x16x32_bf16(al, bh, acc[ct], 0, 0, 0);
                    acc[ct] = __builtin_amdgcn_mfma_f32_16x16x32_bf16(ah, bl, acc[ct], 0, 0, 0);
                }
            }
        }
    }

    // ---- epilogue: bias + relu + store + column stats ----
    // D layout (m89-verified): col = lane&15, row = (lane>>4)*4 + reg
    float cs[8], cq[8];
#pragma unroll
    for (int ct = 0; ct < 8; ++ct) { cs[ct] = 0.f; cq[ct] = 0.f; }
#pragma unroll
    for (int ct = 0; ct < 8; ++ct) {
        int col = ct * 16 + lrow;
        float bias = brel[col];
#pragma unroll
        for (int q = 0; q < 4; ++q) {
            int n = n0 + w * 16 + lk * 4 + q;
            if (n < NN) {
                float o = fmaxf(acc[ct][q] + bias, 0.f);
                hout[(size_t)n * DD + col] = o;
                cs[ct] += o;
                cq[ct] += o * o;
            }
        }
    }
#pragma unroll
    for (int ct = 0; ct < 8; ++ct) {
        cs[ct] += __shfl_xor(cs[ct], 16);
        cs[ct] += __shfl_xor(cs[ct], 32);
        cq[ct] += __shfl_xor(cq[ct], 16);
        cq[ct] += __shfl_xor(cq[ct], 32);
    }
    __syncthreads();  // all Bt reads done; reuse as stats scratch
    float* sb = (float*)Bt_hi;  // [4][128]
    float* qb = (float*)Bt_lo;  // [4][128]
    if (lane < 16) {
#pragma unroll
        for (int ct = 0; ct < 8; ++ct) {
            sb[w * 128 + ct * 16 + lrow] = cs[ct];
            qb[w * 128 + ct * 16 + lrow] = cq[ct];
        }
    }
    __syncthreads();
    if (tid < 128) {
        float s = sb[tid] + sb[128 + tid] + sb[256 + tid] + sb[384 + tid];
        atomicAdd(&stats[tid], s);
    } else {
        int c2 = tid - 128;
        float s = qb[c2] + qb[128 + c2] + qb[256 + c2] + qb[384 + c2];
        atomicAdd(&stats[DD + c2], s);
    }
}

__global__ void k_bn(float* __restrict__ stats, const float* __restrict__ gamma,
                     const float* __restrict__ beta, float* __restrict__ st) {
    int c = threadIdx.x;  // 128 threads
    float mean = stats[c] * (1.0f / NN);
    float var = stats[DD + c] * (1.0f / NN) - mean * mean;
    float s = gamma[c] / sqrtf(var + BN_EPS);
    st[c] = s;
    st[DD + c] = beta[c] - mean * s;
    stats[c] = 0.f;
    stats[DD + c] = 0.f;
}

// ---------------- pooling: contiguous chunks, flush on graph change ----------------

#define POOL_BLOCKS 128

__global__ __launch_bounds__(256) void k_pool(const float* __restrict__ h,
                                              const int* __restrict__ batch,
                                              float* __restrict__ pooled,
                                              float* __restrict__ counts) {
    const int c = threadIdx.x & 127;
    const int half = threadIdx.x >> 7;
    const int chunk = (NN + POOL_BLOCKS - 1) / POOL_BLOCKS;
    int lo = blockIdx.x * chunk;
    int hi = lo + chunk; if (hi > NN) hi = NN;
    float acc = 0.f;
    int cur = -1, cnt = 0;
    for (int n = lo + half; n < hi; n += 2) {
        int g = batch[n];
        float v = h[(size_t)n * DD + c];
        if (g != cur) {
            if (cur >= 0) {
                atomicAdd(&pooled[cur * DD + c], acc);
                if (c == 0) atomicAdd(&counts[cur], (float)cnt);
            }
            cur = g; acc = 0.f; cnt = 0;
        }
        acc += v; cnt++;
    }
    if (cur >= 0) {
        atomicAdd(&pooled[cur * DD + c], acc);
        if (c == 0) atomicAdd(&counts[cur], (float)cnt);
    }
}

// ---------------- head ----------------

__global__ __launch_bounds__(1024) void k_head(const float* __restrict__ pooled,
                                               const float* __restrict__ counts,
                                               const float* __restrict__ st,
                                               const float* __restrict__ dw,
                                               const float* __restrict__ db,
                                               const float* __restrict__ muw,
                                               const float* __restrict__ mub,
                                               float* __restrict__ out) {
    __shared__ float pm[NG][DD];
    __shared__ float zs[NG][DD];
    int t = threadIdx.x;
    int g = t >> 7, c = t & 127;
    float cntg = counts[g];
    pm[g][c] = fmaf(st[c], pooled[g * DD + c], st[DD + c] * cntg) / fmaxf(cntg, 1.0f);
    __syncthreads();
    float acc = 0.f;
    for (int k = 0; k < DD; ++k)
        acc = fmaf(pm[g][k], dw[k * DD + c], acc);
    float z = fmaxf(acc + db[c], 0.f);
    zs[g][c] = z * muw[c];
    __syncthreads();
    if (c == 0) {
        float s = 0.f;
        for (int k = 0; k < DD; ++k) s += zs[g][k];
        out[g] = s + mub[0];
    }
}

// ---------------- host ----------------

extern "C" void kernel_launch(void* const* d_in, const int* in_sizes, int n_in,
                              void* d_out, int out_size, void* d_ws, size_t ws_size,
                              hipStream_t stream) {
    const float* x      = (const float*)d_in[0];
    const int*   ei     = (const int*)d_in[1];
    const int*   batch  = (const int*)d_in[2];
    const float* W_rel  = (const float*)d_in[3];
    const float* b_rel  = (const float*)d_in[4];
    const float* W_root = (const float*)d_in[5];
    const float* gamma  = (const float*)d_in[6];
    const float* beta   = (const float*)d_in[7];
    const float* dw     = (const float*)d_in[8];
    const float* db     = (const float*)d_in[9];
    const float* muw    = (const float*)d_in[10];
    const float* mub    = (const float*)d_in[11];
    float* out = (float*)d_out;

    char* w = (char*)d_ws;
    auto alloc = [&](size_t bytes) {
        char* p = w;
        w += (bytes + 255) & ~(size_t)255;
        return p;
    };
    int*    deg    = (int*)alloc((size_t)NN * 4);
    int*    off    = (int*)alloc((size_t)(NN + 1) * 4);
    int*    cur    = (int*)alloc((size_t)NN * 4);
    int*    csr    = (int*)alloc((size_t)NE * 4);
    float*  hA     = (float*)alloc((size_t)NN * DD * 4);
    float*  hB     = (float*)alloc((size_t)NN * DD * 4);
    float*  aggb   = (float*)alloc((size_t)NN * DD * 4);
    float*  stats  = (float*)alloc(2 * DD * 4);
    float*  st     = (float*)alloc(2 * DD * 4);
    float*  pooled = (float*)alloc(NG * DD * 4);
    float*  counts = (float*)alloc(NG * 4);
    __bf16* wbuf   = (__bf16*)alloc((size_t)NLAYERS * 2 * 2 * DD * DD * 2);

    const int* src = ei;
    const int* dst = ei + NE;

    hipMemsetAsync(deg, 0, (size_t)NN * 4, stream);
    hipMemsetAsync(stats, 0, 2 * DD * 4, stream);
    k_hist<<<2048, 256, 0, stream>>>(dst, deg);
    k_scan<<<1, 1024, 0, stream>>>(deg, off, cur);
    k_scatter<<<2048, 256, 0, stream>>>(src, dst, cur, csr);
    k_init_st<<<1, 256, 0, stream>>>(st);
    k_wprep<<<96, 256, 0, stream>>>(W_rel, W_root, wbuf);

    const float* hcur = x;
    float* bufs[2] = {hA, hB};
    for (int i = 0; i < NLAYERS; ++i) {
        float* hnext = bufs[i & 1];
        k_agg<<<(NN * 64 + 255) / 256, 256, 0, stream>>>(hcur, off, csr, st, aggb);
        k_gemm<<<(NN + 63) / 64, 256, 0, stream>>>(
            aggb, hcur, st,
            wbuf + (size_t)(i * 2 + 0) * 32768,
            wbuf + (size_t)(i * 2 + 1) * 32768,
            b_rel + (size_t)i * DD, hnext, stats);
        k_bn<<<1, 128, 0, stream>>>(stats, gamma + (size_t)i * DD, beta + (size_t)i * DD, st);
        hcur = hnext;
    }
    hipMemsetAsync(pooled, 0, (size_t)NG * DD * 4, stream);
    hipMemsetAsync(counts, 0, (size_t)NG * 4, stream);
    k_pool<<<POOL_BLOCKS, 256, 0, stream>>>(hcur, batch, pooled, counts);
    k_head<<<1, 1024, 0, stream>>>(pooled, counts, st, dw, db, muw, mub, out);
}

// Round 6
// 992.834 us; speedup vs baseline: 2.0562x; 1.2784x over previous
//
#include <hip/hip_runtime.h>

#define NN 50000
#define NE 1600000
#define DD 128
#define NLAYERS 6
#define NG 8
#define BN_EPS 1e-5f

#define NBIN 196       // bins of 256 dst nodes
#define BINCAP 10240   // avg 8163/bin, sigma~90 -> +22 sigma headroom
#define EPB 8192       // edges per k_part block

typedef __bf16 bf16x8 __attribute__((ext_vector_type(8)));
typedef float f32x4 __attribute__((ext_vector_type(4)));

// ---------------- CSR build: 2-pass bin partition ----------------

__global__ __launch_bounds__(1024) void k_part(const int* __restrict__ src,
                                               const int* __restrict__ dst,
                                               int* __restrict__ bincur,
                                               int2* __restrict__ scratch) {
    __shared__ int lh[NBIN], lbase[NBIN];
    const int t = threadIdx.x;
    const int e0 = blockIdx.x * EPB;
    int s8[8], d8[8];
#pragma unroll
    for (int j = 0; j < 8; ++j) {
        int e = e0 + j * 1024 + t;
        if (e < NE) { s8[j] = src[e]; d8[j] = dst[e]; }
        else d8[j] = -1;
    }
    if (t < NBIN) lh[t] = 0;
    __syncthreads();
#pragma unroll
    for (int j = 0; j < 8; ++j)
        if (d8[j] >= 0) atomicAdd(&lh[d8[j] >> 8], 1);
    __syncthreads();
    if (t < NBIN) {
        int c = lh[t];
        lbase[t] = c ? atomicAdd(&bincur[t], c) : 0;  // one global atomic per (block,bin)
        lh[t] = 0;                                     // reuse as local cursor
    }
    __syncthreads();
#pragma unroll
    for (int j = 0; j < 8; ++j)
        if (d8[j] >= 0) {
            int b = d8[j] >> 8;
            int p = lbase[b] + atomicAdd(&lh[b], 1);
            if (p < BINCAP) scratch[(size_t)b * BINCAP + p] = make_int2(s8[j], d8[j]);
        }
}

__global__ __launch_bounds__(256) void k_binscan(const int* __restrict__ bincur,
                                                 int* __restrict__ binbase,
                                                 int* __restrict__ off) {
    __shared__ int sc[256];
    int t = threadIdx.x;
    sc[t] = (t < NBIN) ? bincur[t] : 0;
    __syncthreads();
    for (int d = 1; d < 256; d <<= 1) {
        int v = (t >= d) ? sc[t - d] : 0;
        __syncthreads();
        sc[t] += v;
        __syncthreads();
    }
    binbase[t] = (t == 0) ? 0 : sc[t - 1];
    if (t == 0) off[NN] = NE;
}

__global__ __launch_bounds__(1024) void k_csr(const int* __restrict__ bincur,
                                              const int* __restrict__ binbase,
                                              const int2* __restrict__ scratch,
                                              int* __restrict__ off,
                                              int* __restrict__ csr) {
    __shared__ int nh[256], no[256], ncur[256];
    const int t = threadIdx.x;
    const int b = blockIdx.x;
    int cnt = bincur[b]; if (cnt > BINCAP) cnt = BINCAP;
    const int base = binbase[b];
    if (t < 256) nh[t] = 0;
    __syncthreads();
    for (int i = t; i < cnt; i += 1024) {
        int2 p = scratch[(size_t)b * BINCAP + i];
        atomicAdd(&nh[p.y & 255], 1);
    }
    __syncthreads();
    if (t < 256) no[t] = nh[t];
    __syncthreads();
    for (int d = 1; d < 256; d <<= 1) {
        int v = 0;
        if (t < 256 && t >= d) v = no[t - d];
        __syncthreads();
        if (t < 256) no[t] += v;
        __syncthreads();
    }
    if (t < 256) {
        int excl = (t == 0) ? 0 : no[t - 1];
        ncur[t] = excl;
        int n = b * 256 + t;
        if (n < NN) off[n] = base + excl;
    }
    __syncthreads();
    for (int i = t; i < cnt; i += 1024) {
        int2 p = scratch[(size_t)b * BINCAP + i];
        int pos = atomicAdd(&ncur[p.y & 255], 1);
        csr[base + pos] = p.x;  // writes confined to this bin's ~32KB window
    }
}

__global__ void k_init_st(float* __restrict__ st) {
    int t = threadIdx.x;
    st[t] = (t < DD) ? 1.f : 0.f;
}

// ---------------- weight prep: f32 [k][n] -> packed bf16 hi/lo transposed [n][k] ----

__global__ __launch_bounds__(256) void k_wprep(const float* __restrict__ Wrel,
                                               const float* __restrict__ Wroot,
                                               __bf16* __restrict__ wbuf) {
    int g = blockIdx.x * 256 + threadIdx.x;   // 24576 tasks
    int li = g >> 11;                          // layer*2 + input
    int rest = g & 2047;
    int k8 = rest >> 7;
    int n = rest & 127;
    int layer = li >> 1, input = li & 1;
    const float* src = (input ? Wroot : Wrel) + (size_t)layer * DD * DD;
    bf16x8 vh, vl;
#pragma unroll
    for (int j = 0; j < 8; ++j) {
        float v = src[(size_t)(k8 * 8 + j) * DD + n];
        __bf16 hb = (__bf16)v;
        vh[j] = hb;
        vl[j] = (__bf16)(v - (float)hb);
    }
    __bf16* dh = wbuf + (size_t)li * 32768 + n * DD + k8 * 8;
    *(bf16x8*)dh = vh;
    *(bf16x8*)(dh + 16384) = vl;
}

// ---------------- aggregation: one wave per dst node ----------------

__global__ __launch_bounds__(256) void k_agg(const float* __restrict__ h,
                                             const int* __restrict__ off,
                                             const int* __restrict__ csr,
                                             const float* __restrict__ st,
                                             float* __restrict__ agg) {
    int w = (blockIdx.x * blockDim.x + threadIdx.x) >> 6;
    int lane = threadIdx.x & 63;
    if (w >= NN) return;
    int lo = off[w], hi = off[w + 1];
    const int half = lane >> 5;
    const int colq = lane & 31;
    const float4* hp = (const float4*)h;
    float4 acc = make_float4(0.f, 0.f, 0.f, 0.f);
    int e = lo;
    for (; e + 8 <= hi; e += 8) {
        int s0 = csr[e     + half];
        int s1 = csr[e + 2 + half];
        int s2 = csr[e + 4 + half];
        int s3 = csr[e + 6 + half];
        float4 v0 = hp[(size_t)s0 * 32 + colq];
        float4 v1 = hp[(size_t)s1 * 32 + colq];
        float4 v2 = hp[(size_t)s2 * 32 + colq];
        float4 v3 = hp[(size_t)s3 * 32 + colq];
        acc.x += (v0.x + v1.x) + (v2.x + v3.x);
        acc.y += (v0.y + v1.y) + (v2.y + v3.y);
        acc.z += (v0.z + v1.z) + (v2.z + v3.z);
        acc.w += (v0.w + v1.w) + (v2.w + v3.w);
    }
    for (; e + 2 <= hi; e += 2) {
        int s = csr[e + half];
        float4 v = hp[(size_t)s * 32 + colq];
        acc.x += v.x; acc.y += v.y; acc.z += v.z; acc.w += v.w;
    }
    acc.x += __shfl_xor(acc.x, 32);
    acc.y += __shfl_xor(acc.y, 32);
    acc.z += __shfl_xor(acc.z, 32);
    acc.w += __shfl_xor(acc.w, 32);
    if (e < hi) {
        int s = csr[hi - 1];
        float4 v = hp[(size_t)s * 32 + colq];
        acc.x += v.x; acc.y += v.y; acc.z += v.z; acc.w += v.w;
    }
    float degf = (float)(hi - lo);
    float4 s4 = *(const float4*)(st + colq * 4);
    float4 t4 = *(const float4*)(st + DD + colq * 4);
    float4 o;
    o.x = fmaf(s4.x, acc.x, t4.x * degf);
    o.y = fmaf(s4.y, acc.y, t4.y * degf);
    o.z = fmaf(s4.z, acc.z, t4.z * degf);
    o.w = fmaf(s4.w, acc.w, t4.w * degf);
    if (lane < 32) ((float4*)agg)[(size_t)w * 32 + colq] = o;
}

// ---------------- MFMA GEMM (split-bf16 x3) + bias + relu + stats ----------------

__global__ __launch_bounds__(256) void k_gemm(const float* __restrict__ agg,
                                              const float* __restrict__ hraw,
                                              const float* __restrict__ st,
                                              const __bf16* __restrict__ wrel_pk,
                                              const __bf16* __restrict__ wroot_pk,
                                              const float* __restrict__ brel,
                                              float* __restrict__ hout,
                                              float* __restrict__ stats) {
    __shared__ __align__(16) __bf16 A_hi[64 * 128];
    __shared__ __align__(16) __bf16 A_lo[64 * 128];
    __shared__ __align__(16) __bf16 Bt_hi[128 * 64];
    __shared__ __align__(16) __bf16 Bt_lo[128 * 64];
    const int tid = threadIdx.x;
    const int n0 = blockIdx.x * 64;
    const int w = tid >> 6, lane = tid & 63;
    const int lrow = lane & 15, lk = lane >> 4;
    const int arow = w * 16 + lrow;

    f32x4 acc[8];
#pragma unroll
    for (int ct = 0; ct < 8; ++ct) acc[ct] = (f32x4){0.f, 0.f, 0.f, 0.f};

    for (int p = 0; p < 2; ++p) {
        const float* Asrc = p ? hraw : agg;
        const __bf16* wb = p ? wroot_pk : wrel_pk;
        __syncthreads();
#pragma unroll
        for (int rep = 0; rep < 4; ++rep) {
            int idx = rep * 256 + tid;
            int r = idx >> 4, chunk = idx & 15;
            int n = n0 + r;
            float v[8];
            if (n < NN) {
                float4 a = *(const float4*)(Asrc + (size_t)n * DD + chunk * 8);
                float4 b = *(const float4*)(Asrc + (size_t)n * DD + chunk * 8 + 4);
                v[0] = a.x; v[1] = a.y; v[2] = a.z; v[3] = a.w;
                v[4] = b.x; v[5] = b.y; v[6] = b.z; v[7] = b.w;
                if (p) {
#pragma unroll
                    for (int j = 0; j < 8; ++j) {
                        int k = chunk * 8 + j;
                        v[j] = fmaf(st[k], v[j], st[DD + k]);
                    }
                }
            } else {
#pragma unroll
                for (int j = 0; j < 8; ++j) v[j] = 0.f;
            }
            bf16x8 vh, vl;
#pragma unroll
            for (int j = 0; j < 8; ++j) {
                __bf16 hb = (__bf16)v[j];
                vh[j] = hb;
                vl[j] = (__bf16)(v[j] - (float)hb);
            }
            int eo = r * 128 + ((chunk ^ (r & 7)) << 3);
            *(bf16x8*)(A_hi + eo) = vh;
            *(bf16x8*)(A_lo + eo) = vl;
        }
        for (int kh = 0; kh < 2; ++kh) {
            __syncthreads();
#pragma unroll
            for (int rep = 0; rep < 8; ++rep) {
                int idx = rep * 256 + tid;
                int halfsel = idx >> 10;
                int t2 = idx & 1023;
                int c = t2 >> 3, chunk = t2 & 7;
                const uint4* srcp = (const uint4*)(wb + halfsel * 16384 + c * DD + kh * 64 + chunk * 8);
                __bf16* dstp = (halfsel ? Bt_lo : Bt_hi) + c * 64 + ((chunk ^ (c & 7)) << 3);
                *(uint4*)dstp = *srcp;
            }
            __syncthreads();
#pragma unroll
            for (int ks = 0; ks < 2; ++ks) {
                int ks_g = kh * 2 + ks;
                int chA = ks_g * 4 + lk;
                int eoA = arow * 128 + ((chA ^ (arow & 7)) << 3);
                bf16x8 ah = *(const bf16x8*)(A_hi + eoA);
                bf16x8 al = *(const bf16x8*)(A_lo + eoA);
#pragma unroll
                for (int ct = 0; ct < 8; ++ct) {
                    int c = ct * 16 + lrow;
                    int chB = ks * 4 + lk;
                    int eoB = c * 64 + ((chB ^ (c & 7)) << 3);
                    bf16x8 bh = *(const bf16x8*)(Bt_hi + eoB);
                    bf16x8 bl = *(const bf16x8*)(Bt_lo + eoB);
                    acc[ct] = __builtin_amdgcn_mfma_f32_16x16x32_bf16(ah, bh, acc[ct], 0, 0, 0);
                    acc[ct] = __builtin_amdgcn_mfma_f32_16x16x32_bf16(al, bh, acc[ct], 0, 0, 0);
                    acc[ct] = __builtin_amdgcn_mfma_f32_16x16x32_bf16(ah, bl, acc[ct], 0, 0, 0);
                }
            }
        }
    }

    float cs[8], cq[8];
#pragma unroll
    for (int ct = 0; ct < 8; ++ct) { cs[ct] = 0.f; cq[ct] = 0.f; }
#pragma unroll
    for (int ct = 0; ct < 8; ++ct) {
        int col = ct * 16 + lrow;
        float bias = brel[col];
#pragma unroll
        for (int q = 0; q < 4; ++q) {
            int n = n0 + w * 16 + lk * 4 + q;
            if (n < NN) {
                float o = fmaxf(acc[ct][q] + bias, 0.f);
                hout[(size_t)n * DD + col] = o;
                cs[ct] += o;
                cq[ct] += o * o;
            }
        }
    }
#pragma unroll
    for (int ct = 0; ct < 8; ++ct) {
        cs[ct] += __shfl_xor(cs[ct], 16);
        cs[ct] += __shfl_xor(cs[ct], 32);
        cq[ct] += __shfl_xor(cq[ct], 16);
        cq[ct] += __shfl_xor(cq[ct], 32);
    }
    __syncthreads();
    float* sb = (float*)Bt_hi;
    float* qb = (float*)Bt_lo;
    if (lane < 16) {
#pragma unroll
        for (int ct = 0; ct < 8; ++ct) {
            sb[w * 128 + ct * 16 + lrow] = cs[ct];
            qb[w * 128 + ct * 16 + lrow] = cq[ct];
        }
    }
    __syncthreads();
    if (tid < 128) {
        float s = sb[tid] + sb[128 + tid] + sb[256 + tid] + sb[384 + tid];
        atomicAdd(&stats[tid], s);
    } else {
        int c2 = tid - 128;
        float s = qb[c2] + qb[128 + c2] + qb[256 + c2] + qb[384 + c2];
        atomicAdd(&stats[DD + c2], s);
    }
}

__global__ void k_bn(float* __restrict__ stats, const float* __restrict__ gamma,
                     const float* __restrict__ beta, float* __restrict__ st) {
    int c = threadIdx.x;
    float mean = stats[c] * (1.0f / NN);
    float var = stats[DD + c] * (1.0f / NN) - mean * mean;
    float s = gamma[c] / sqrtf(var + BN_EPS);
    st[c] = s;
    st[DD + c] = beta[c] - mean * s;
    stats[c] = 0.f;
    stats[DD + c] = 0.f;
}

// ---------------- pooling ----------------

#define POOL_BLOCKS 128

__global__ __launch_bounds__(256) void k_pool(const float* __restrict__ h,
                                              const int* __restrict__ batch,
                                              float* __restrict__ pooled,
                                              float* __restrict__ counts) {
    const int c = threadIdx.x & 127;
    const int half = threadIdx.x >> 7;
    const int chunk = (NN + POOL_BLOCKS - 1) / POOL_BLOCKS;
    int lo = blockIdx.x * chunk;
    int hi = lo + chunk; if (hi > NN) hi = NN;
    float acc = 0.f;
    int cur = -1, cnt = 0;
    for (int n = lo + half; n < hi; n += 2) {
        int g = batch[n];
        float v = h[(size_t)n * DD + c];
        if (g != cur) {
            if (cur >= 0) {
                atomicAdd(&pooled[cur * DD + c], acc);
                if (c == 0) atomicAdd(&counts[cur], (float)cnt);
            }
            cur = g; acc = 0.f; cnt = 0;
        }
        acc += v; cnt++;
    }
    if (cur >= 0) {
        atomicAdd(&pooled[cur * DD + c], acc);
        if (c == 0) atomicAdd(&counts[cur], (float)cnt);
    }
}

// ---------------- head ----------------

__global__ __launch_bounds__(1024) void k_head(const float* __restrict__ pooled,
                                               const float* __restrict__ counts,
                                               const float* __restrict__ st,
                                               const float* __restrict__ dw,
                                               const float* __restrict__ db,
                                               const float* __restrict__ muw,
                                               const float* __restrict__ mub,
                                               float* __restrict__ out) {
    __shared__ float pm[NG][DD];
    __shared__ float zs[NG][DD];
    int t = threadIdx.x;
    int g = t >> 7, c = t & 127;
    float cntg = counts[g];
    pm[g][c] = fmaf(st[c], pooled[g * DD + c], st[DD + c] * cntg) / fmaxf(cntg, 1.0f);
    __syncthreads();
    float acc = 0.f;
    for (int k = 0; k < DD; ++k)
        acc = fmaf(pm[g][k], dw[k * DD + c], acc);
    float z = fmaxf(acc + db[c], 0.f);
    zs[g][c] = z * muw[c];
    __syncthreads();
    if (c == 0) {
        float s = 0.f;
        for (int k = 0; k < DD; ++k) s += zs[g][k];
        out[g] = s + mub[0];
    }
}

// ---------------- host ----------------

extern "C" void kernel_launch(void* const* d_in, const int* in_sizes, int n_in,
                              void* d_out, int out_size, void* d_ws, size_t ws_size,
                              hipStream_t stream) {
    const float* x      = (const float*)d_in[0];
    const int*   ei     = (const int*)d_in[1];
    const int*   batch  = (const int*)d_in[2];
    const float* W_rel  = (const float*)d_in[3];
    const float* b_rel  = (const float*)d_in[4];
    const float* W_root = (const float*)d_in[5];
    const float* gamma  = (const float*)d_in[6];
    const float* beta   = (const float*)d_in[7];
    const float* dw     = (const float*)d_in[8];
    const float* db     = (const float*)d_in[9];
    const float* muw    = (const float*)d_in[10];
    const float* mub    = (const float*)d_in[11];
    float* out = (float*)d_out;

    char* w = (char*)d_ws;
    auto alloc = [&](size_t bytes) {
        char* p = w;
        w += (bytes + 255) & ~(size_t)255;
        return p;
    };
    int*    off     = (int*)alloc((size_t)(NN + 1) * 4);
    int*    csr     = (int*)alloc((size_t)NE * 4);
    float*  hA      = (float*)alloc((size_t)NN * DD * 4);
    float*  hB      = (float*)alloc((size_t)NN * DD * 4);
    float*  aggb    = (float*)alloc((size_t)NN * DD * 4);  // doubles as partition scratch
    float*  stats   = (float*)alloc(2 * DD * 4);
    float*  st      = (float*)alloc(2 * DD * 4);
    float*  pooled  = (float*)alloc(NG * DD * 4);
    float*  counts  = (float*)alloc(NG * 4);
    int*    bincur  = (int*)alloc(256 * 4);
    int*    binbase = (int*)alloc(256 * 4);
    __bf16* wbuf    = (__bf16*)alloc((size_t)NLAYERS * 2 * 2 * DD * DD * 2);

    const int* src = ei;
    const int* dst = ei + NE;
    int2* scratch = (int2*)aggb;  // NBIN*BINCAP*8 = 16.06 MB <= 25.6 MB

    hipMemsetAsync(bincur, 0, 256 * 4, stream);
    hipMemsetAsync(stats, 0, 2 * DD * 4, stream);
    k_part<<<(NE + EPB - 1) / EPB, 1024, 0, stream>>>(src, dst, bincur, scratch);
    k_binscan<<<1, 256, 0, stream>>>(bincur, binbase, off);
    k_csr<<<NBIN, 1024, 0, stream>>>(bincur, binbase, scratch, off, csr);
    k_init_st<<<1, 256, 0, stream>>>(st);
    k_wprep<<<96, 256, 0, stream>>>(W_rel, W_root, wbuf);

    const float* hcur = x;
    float* bufs[2] = {hA, hB};
    for (int i = 0; i < NLAYERS; ++i) {
        float* hnext = bufs[i & 1];
        k_agg<<<(NN * 64 + 255) / 256, 256, 0, stream>>>(hcur, off, csr, st, aggb);
        k_gemm<<<(NN + 63) / 64, 256, 0, stream>>>(
            aggb, hcur, st,
            wbuf + (size_t)(i * 2 + 0) * 32768,
            wbuf + (size_t)(i * 2 + 1) * 32768,
            b_rel + (size_t)i * DD, hnext, stats);
        k_bn<<<1, 128, 0, stream>>>(stats, gamma + (size_t)i * DD, beta + (size_t)i * DD, st);
        hcur = hnext;
    }
    hipMemsetAsync(pooled, 0, (size_t)NG * DD * 4, stream);
    hipMemsetAsync(counts, 0, (size_t)NG * 4, stream);
    k_pool<<<POOL_BLOCKS, 256, 0, stream>>>(hcur, batch, pooled, counts);
    k_head<<<1, 1024, 0, stream>>>(pooled, counts, st, dw, db, muw, mub, out);
}

// Round 7
// 701.835 us; speedup vs baseline: 2.9088x; 1.4146x over previous
//
#include <hip/hip_runtime.h>

#define NN 50000
#define NE 1600000
#define DD 128
#define NLAYERS 6
#define NG 8
#define BN_EPS 1e-5f

#define NBIN 196       // bins of 256 dst nodes
#define BINCAP 10240   // avg 8163/bin, sigma~90 -> +22 sigma headroom
#define EPB 8192       // edges per k_part block

typedef __bf16 bf16x8 __attribute__((ext_vector_type(8)));
typedef float f32x4 __attribute__((ext_vector_type(4)));

static __device__ __forceinline__ float bflo(unsigned u) {
    return __uint_as_float(u << 16);
}
static __device__ __forceinline__ float bfhi(unsigned u) {
    return __uint_as_float(u & 0xffff0000u);
}
static __device__ __forceinline__ unsigned pkbf(float a, float b) {
    __bf16 x = (__bf16)a, y = (__bf16)b;
    return (unsigned)*(unsigned short*)&x | ((unsigned)*(unsigned short*)&y << 16);
}

// ---------------- CSR build: 2-pass bin partition (R6-proven) ----------------

__global__ __launch_bounds__(1024) void k_part(const int* __restrict__ src,
                                               const int* __restrict__ dst,
                                               int* __restrict__ bincur,
                                               int2* __restrict__ scratch) {
    __shared__ int lh[NBIN], lbase[NBIN];
    const int t = threadIdx.x;
    const int e0 = blockIdx.x * EPB;
    int s8[8], d8[8];
#pragma unroll
    for (int j = 0; j < 8; ++j) {
        int e = e0 + j * 1024 + t;
        if (e < NE) { s8[j] = src[e]; d8[j] = dst[e]; }
        else d8[j] = -1;
    }
    if (t < NBIN) lh[t] = 0;
    __syncthreads();
#pragma unroll
    for (int j = 0; j < 8; ++j)
        if (d8[j] >= 0) atomicAdd(&lh[d8[j] >> 8], 1);
    __syncthreads();
    if (t < NBIN) {
        int c = lh[t];
        lbase[t] = c ? atomicAdd(&bincur[t], c) : 0;
        lh[t] = 0;
    }
    __syncthreads();
#pragma unroll
    for (int j = 0; j < 8; ++j)
        if (d8[j] >= 0) {
            int b = d8[j] >> 8;
            int p = lbase[b] + atomicAdd(&lh[b], 1);
            if (p < BINCAP) scratch[(size_t)b * BINCAP + p] = make_int2(s8[j], d8[j]);
        }
}

__global__ __launch_bounds__(256) void k_binscan(const int* __restrict__ bincur,
                                                 int* __restrict__ binbase,
                                                 int* __restrict__ off) {
    __shared__ int sc[256];
    int t = threadIdx.x;
    sc[t] = (t < NBIN) ? bincur[t] : 0;
    __syncthreads();
    for (int d = 1; d < 256; d <<= 1) {
        int v = (t >= d) ? sc[t - d] : 0;
        __syncthreads();
        sc[t] += v;
        __syncthreads();
    }
    binbase[t] = (t == 0) ? 0 : sc[t - 1];
    if (t == 0) off[NN] = NE;
}

__global__ __launch_bounds__(1024) void k_csr(const int* __restrict__ bincur,
                                              const int* __restrict__ binbase,
                                              const int2* __restrict__ scratch,
                                              int* __restrict__ off,
                                              int* __restrict__ csr) {
    __shared__ int nh[256], no[256], ncur[256];
    const int t = threadIdx.x;
    const int b = blockIdx.x;
    int cnt = bincur[b]; if (cnt > BINCAP) cnt = BINCAP;
    const int base = binbase[b];
    if (t < 256) nh[t] = 0;
    __syncthreads();
    for (int i = t; i < cnt; i += 1024) {
        int2 p = scratch[(size_t)b * BINCAP + i];
        atomicAdd(&nh[p.y & 255], 1);
    }
    __syncthreads();
    if (t < 256) no[t] = nh[t];
    __syncthreads();
    for (int d = 1; d < 256; d <<= 1) {
        int v = 0;
        if (t < 256 && t >= d) v = no[t - d];
        __syncthreads();
        if (t < 256) no[t] += v;
        __syncthreads();
    }
    if (t < 256) {
        int excl = (t == 0) ? 0 : no[t - 1];
        ncur[t] = excl;
        int n = b * 256 + t;
        if (n < NN) off[n] = base + excl;
    }
    __syncthreads();
    for (int i = t; i < cnt; i += 1024) {
        int2 p = scratch[(size_t)b * BINCAP + i];
        int pos = atomicAdd(&ncur[p.y & 255], 1);
        csr[base + pos] = p.x;
    }
}

__global__ void k_init_st(float* __restrict__ st) {
    int t = threadIdx.x;
    st[t] = (t < DD) ? 1.f : 0.f;
}

// ---------------- x -> bf16 copy ----------------

__global__ __launch_bounds__(256) void k_xtobf(const float* __restrict__ x,
                                               unsigned short* __restrict__ xb) {
    size_t i = (size_t)(blockIdx.x * 256 + threadIdx.x) * 8;  // 800000 tasks
    float4 a = *(const float4*)(x + i);
    float4 b = *(const float4*)(x + i + 4);
    uint4 o;
    o.x = pkbf(a.x, a.y); o.y = pkbf(a.z, a.w);
    o.z = pkbf(b.x, b.y); o.w = pkbf(b.z, b.w);
    *(uint4*)(xb + i) = o;
}

// ---------------- weight prep: f32 [k][n] -> packed bf16 hi/lo transposed [n][k] ----

__global__ __launch_bounds__(256) void k_wprep(const float* __restrict__ Wrel,
                                               const float* __restrict__ Wroot,
                                               __bf16* __restrict__ wbuf) {
    int g = blockIdx.x * 256 + threadIdx.x;   // 24576 tasks
    int li = g >> 11;
    int rest = g & 2047;
    int k8 = rest >> 7;
    int n = rest & 127;
    int layer = li >> 1, input = li & 1;
    const float* src = (input ? Wroot : Wrel) + (size_t)layer * DD * DD;
    bf16x8 vh, vl;
#pragma unroll
    for (int j = 0; j < 8; ++j) {
        float v = src[(size_t)(k8 * 8 + j) * DD + n];
        __bf16 hb = (__bf16)v;
        vh[j] = hb;
        vl[j] = (__bf16)(v - (float)hb);
    }
    __bf16* dh = wbuf + (size_t)li * 32768 + n * DD + k8 * 8;
    *(bf16x8*)dh = vh;
    *(bf16x8*)(dh + 16384) = vl;
}

// ---------------- aggregation: one wave per dst node, bf16 rows, 4 row-streams ----
// agg'[n][c] = s[c] * sum_{j in N(n)} h16[j][c] + t[c] * deg(n)

#define ACC8(v) {                                              \
    a0 += bflo(v.x); a1 += bfhi(v.x);                          \
    a2 += bflo(v.y); a3 += bfhi(v.y);                          \
    a4 += bflo(v.z); a5 += bfhi(v.z);                          \
    a6 += bflo(v.w); a7 += bfhi(v.w); }

__global__ __launch_bounds__(256) void k_agg(const unsigned short* __restrict__ hb,
                                             const int* __restrict__ off,
                                             const int* __restrict__ csr,
                                             const float* __restrict__ st,
                                             float* __restrict__ agg) {
    int w = (blockIdx.x * blockDim.x + threadIdx.x) >> 6;
    int lane = threadIdx.x & 63;
    if (w >= NN) return;
    int lo = off[w], hi = off[w + 1];
    const int q = lane >> 4;      // which edge of the 4-group
    const int colo = lane & 15;   // col octet (8 bf16 = 16B)
    const uint4* hp = (const uint4*)hb;   // row stride = 16 uint4
    float a0 = 0.f, a1 = 0.f, a2 = 0.f, a3 = 0.f, a4 = 0.f, a5 = 0.f, a6 = 0.f, a7 = 0.f;
    int e = lo;
    for (; e + 8 <= hi; e += 8) {
        int s0 = csr[e + q];
        int s1 = csr[e + 4 + q];
        uint4 v0 = hp[(size_t)s0 * 16 + colo];
        uint4 v1 = hp[(size_t)s1 * 16 + colo];
        ACC8(v0);
        ACC8(v1);
    }
    for (; e + 4 <= hi; e += 4) {
        int s = csr[e + q];
        uint4 v = hp[(size_t)s * 16 + colo];
        ACC8(v);
    }
    // combine the four row-streams; every lane ends with the full sum for its colo
    a0 += __shfl_xor(a0, 16); a1 += __shfl_xor(a1, 16);
    a2 += __shfl_xor(a2, 16); a3 += __shfl_xor(a3, 16);
    a4 += __shfl_xor(a4, 16); a5 += __shfl_xor(a5, 16);
    a6 += __shfl_xor(a6, 16); a7 += __shfl_xor(a7, 16);
    a0 += __shfl_xor(a0, 32); a1 += __shfl_xor(a1, 32);
    a2 += __shfl_xor(a2, 32); a3 += __shfl_xor(a3, 32);
    a4 += __shfl_xor(a4, 32); a5 += __shfl_xor(a5, 32);
    a6 += __shfl_xor(a6, 32); a7 += __shfl_xor(a7, 32);
    // tail (<4 edges): all lanes add identical values -> replicas stay equal
    for (; e < hi; ++e) {
        int s = csr[e];
        uint4 v = hp[(size_t)s * 16 + colo];
        ACC8(v);
    }
    if (lane < 16) {
        float degf = (float)(hi - lo);
        float4 sA = *(const float4*)(st + colo * 8);
        float4 sB = *(const float4*)(st + colo * 8 + 4);
        float4 tA = *(const float4*)(st + DD + colo * 8);
        float4 tB = *(const float4*)(st + DD + colo * 8 + 4);
        float4 oA, oB;
        oA.x = fmaf(sA.x, a0, tA.x * degf);
        oA.y = fmaf(sA.y, a1, tA.y * degf);
        oA.z = fmaf(sA.z, a2, tA.z * degf);
        oA.w = fmaf(sA.w, a3, tA.w * degf);
        oB.x = fmaf(sB.x, a4, tB.x * degf);
        oB.y = fmaf(sB.y, a5, tB.y * degf);
        oB.z = fmaf(sB.z, a6, tB.z * degf);
        oB.w = fmaf(sB.w, a7, tB.w * degf);
        ((float4*)agg)[(size_t)w * 32 + colo * 2] = oA;
        ((float4*)agg)[(size_t)w * 32 + colo * 2 + 1] = oB;
    }
}

// ---------------- MFMA GEMM (split-bf16 x3) + bias + relu + stats ----------------
// Block = 64 rows x 128 cols, 4 waves. Output stored as bf16 (RNE).

__global__ __launch_bounds__(256) void k_gemm(const float* __restrict__ agg,
                                              const unsigned short* __restrict__ hb_in,
                                              const float* __restrict__ st,
                                              const __bf16* __restrict__ wrel_pk,
                                              const __bf16* __restrict__ wroot_pk,
                                              const float* __restrict__ brel,
                                              unsigned short* __restrict__ hb_out,
                                              float* __restrict__ stats) {
    __shared__ __align__(16) __bf16 A_hi[64 * 128];
    __shared__ __align__(16) __bf16 A_lo[64 * 128];
    __shared__ __align__(16) __bf16 Bt_hi[128 * 64];
    __shared__ __align__(16) __bf16 Bt_lo[128 * 64];
    const int tid = threadIdx.x;
    const int n0 = blockIdx.x * 64;
    const int w = tid >> 6, lane = tid & 63;
    const int lrow = lane & 15, lk = lane >> 4;
    const int arow = w * 16 + lrow;

    f32x4 acc[8];
#pragma unroll
    for (int ct = 0; ct < 8; ++ct) acc[ct] = (f32x4){0.f, 0.f, 0.f, 0.f};

    for (int p = 0; p < 2; ++p) {
        const __bf16* wb = p ? wroot_pk : wrel_pk;
        __syncthreads();
#pragma unroll
        for (int rep = 0; rep < 4; ++rep) {
            int idx = rep * 256 + tid;
            int r = idx >> 4, chunk = idx & 15;
            int n = n0 + r;
            float v[8];
            if (n < NN) {
                if (p == 0) {
                    float4 a = *(const float4*)(agg + (size_t)n * DD + chunk * 8);
                    float4 b = *(const float4*)(agg + (size_t)n * DD + chunk * 8 + 4);
                    v[0] = a.x; v[1] = a.y; v[2] = a.z; v[3] = a.w;
                    v[4] = b.x; v[5] = b.y; v[6] = b.z; v[7] = b.w;
                } else {
                    uint4 u = *(const uint4*)(hb_in + (size_t)n * DD + chunk * 8);
                    v[0] = bflo(u.x); v[1] = bfhi(u.x);
                    v[2] = bflo(u.y); v[3] = bfhi(u.y);
                    v[4] = bflo(u.z); v[5] = bfhi(u.z);
                    v[6] = bflo(u.w); v[7] = bfhi(u.w);
#pragma unroll
                    for (int j = 0; j < 8; ++j) {
                        int k = chunk * 8 + j;
                        v[j] = fmaf(st[k], v[j], st[DD + k]);
                    }
                }
            } else {
#pragma unroll
                for (int j = 0; j < 8; ++j) v[j] = 0.f;
            }
            bf16x8 vh, vl;
#pragma unroll
            for (int j = 0; j < 8; ++j) {
                __bf16 hbv = (__bf16)v[j];
                vh[j] = hbv;
                vl[j] = (__bf16)(v[j] - (float)hbv);
            }
            int eo = r * 128 + ((chunk ^ (r & 7)) << 3);
            *(bf16x8*)(A_hi + eo) = vh;
            *(bf16x8*)(A_lo + eo) = vl;
        }
        for (int kh = 0; kh < 2; ++kh) {
            __syncthreads();
#pragma unroll
            for (int rep = 0; rep < 8; ++rep) {
                int idx = rep * 256 + tid;
                int halfsel = idx >> 10;
                int t2 = idx & 1023;
                int c = t2 >> 3, chunk = t2 & 7;
                const uint4* srcp = (const uint4*)(wb + halfsel * 16384 + c * DD + kh * 64 + chunk * 8);
                __bf16* dstp = (halfsel ? Bt_lo : Bt_hi) + c * 64 + ((chunk ^ (c & 7)) << 3);
                *(uint4*)dstp = *srcp;
            }
            __syncthreads();
#pragma unroll
            for (int ks = 0; ks < 2; ++ks) {
                int ks_g = kh * 2 + ks;
                int chA = ks_g * 4 + lk;
                int eoA = arow * 128 + ((chA ^ (arow & 7)) << 3);
                bf16x8 ah = *(const bf16x8*)(A_hi + eoA);
                bf16x8 al = *(const bf16x8*)(A_lo + eoA);
#pragma unroll
                for (int ct = 0; ct < 8; ++ct) {
                    int c = ct * 16 + lrow;
                    int chB = ks * 4 + lk;
                    int eoB = c * 64 + ((chB ^ (c & 7)) << 3);
                    bf16x8 bh = *(const bf16x8*)(Bt_hi + eoB);
                    bf16x8 bl = *(const bf16x8*)(Bt_lo + eoB);
                    acc[ct] = __builtin_amdgcn_mfma_f32_16x16x32_bf16(ah, bh, acc[ct], 0, 0, 0);
                    acc[ct] = __builtin_amdgcn_mfma_f32_16x16x32_bf16(al, bh, acc[ct], 0, 0, 0);
                    acc[ct] = __builtin_amdgcn_mfma_f32_16x16x32_bf16(ah, bl, acc[ct], 0, 0, 0);
                }
            }
        }
    }

    float cs[8], cq[8];
#pragma unroll
    for (int ct = 0; ct < 8; ++ct) { cs[ct] = 0.f; cq[ct] = 0.f; }
#pragma unroll
    for (int ct = 0; ct < 8; ++ct) {
        int col = ct * 16 + lrow;
        float bias = brel[col];
#pragma unroll
        for (int q = 0; q < 4; ++q) {
            int n = n0 + w * 16 + lk * 4 + q;
            if (n < NN) {
                float o = fmaxf(acc[ct][q] + bias, 0.f);
                __bf16 ob = (__bf16)o;
                hb_out[(size_t)n * DD + col] = *(unsigned short*)&ob;
                cs[ct] += o;
                cq[ct] += o * o;
            }
        }
    }
#pragma unroll
    for (int ct = 0; ct < 8; ++ct) {
        cs[ct] += __shfl_xor(cs[ct], 16);
        cs[ct] += __shfl_xor(cs[ct], 32);
        cq[ct] += __shfl_xor(cq[ct], 16);
        cq[ct] += __shfl_xor(cq[ct], 32);
    }
    __syncthreads();
    float* sb = (float*)Bt_hi;
    float* qb = (float*)Bt_lo;
    if (lane < 16) {
#pragma unroll
        for (int ct = 0; ct < 8; ++ct) {
            sb[w * 128 + ct * 16 + lrow] = cs[ct];
            qb[w * 128 + ct * 16 + lrow] = cq[ct];
        }
    }
    __syncthreads();
    if (tid < 128) {
        float s = sb[tid] + sb[128 + tid] + sb[256 + tid] + sb[384 + tid];
        atomicAdd(&stats[tid], s);
    } else {
        int c2 = tid - 128;
        float s = qb[c2] + qb[128 + c2] + qb[256 + c2] + qb[384 + c2];
        atomicAdd(&stats[DD + c2], s);
    }
}

__global__ void k_bn(float* __restrict__ stats, const float* __restrict__ gamma,
                     const float* __restrict__ beta, float* __restrict__ st) {
    int c = threadIdx.x;
    float mean = stats[c] * (1.0f / NN);
    float var = stats[DD + c] * (1.0f / NN) - mean * mean;
    float s = gamma[c] / sqrtf(var + BN_EPS);
    st[c] = s;
    st[DD + c] = beta[c] - mean * s;
    stats[c] = 0.f;
    stats[DD + c] = 0.f;
}

// ---------------- pooling (bf16 input) ----------------

#define POOL_BLOCKS 128

__global__ __launch_bounds__(256) void k_pool(const unsigned short* __restrict__ hb,
                                              const int* __restrict__ batch,
                                              float* __restrict__ pooled,
                                              float* __restrict__ counts) {
    const int c = threadIdx.x & 127;
    const int half = threadIdx.x >> 7;
    const int chunk = (NN + POOL_BLOCKS - 1) / POOL_BLOCKS;
    int lo = blockIdx.x * chunk;
    int hi = lo + chunk; if (hi > NN) hi = NN;
    float acc = 0.f;
    int cur = -1, cnt = 0;
    for (int n = lo + half; n < hi; n += 2) {
        int g = batch[n];
        float v = __uint_as_float((unsigned)hb[(size_t)n * DD + c] << 16);
        if (g != cur) {
            if (cur >= 0) {
                atomicAdd(&pooled[cur * DD + c], acc);
                if (c == 0) atomicAdd(&counts[cur], (float)cnt);
            }
            cur = g; acc = 0.f; cnt = 0;
        }
        acc += v; cnt++;
    }
    if (cur >= 0) {
        atomicAdd(&pooled[cur * DD + c], acc);
        if (c == 0) atomicAdd(&counts[cur], (float)cnt);
    }
}

// ---------------- head ----------------

__global__ __launch_bounds__(1024) void k_head(const float* __restrict__ pooled,
                                               const float* __restrict__ counts,
                                               const float* __restrict__ st,
                                               const float* __restrict__ dw,
                                               const float* __restrict__ db,
                                               const float* __restrict__ muw,
                                               const float* __restrict__ mub,
                                               float* __restrict__ out) {
    __shared__ float pm[NG][DD];
    __shared__ float zs[NG][DD];
    int t = threadIdx.x;
    int g = t >> 7, c = t & 127;
    float cntg = counts[g];
    pm[g][c] = fmaf(st[c], pooled[g * DD + c], st[DD + c] * cntg) / fmaxf(cntg, 1.0f);
    __syncthreads();
    float acc = 0.f;
    for (int k = 0; k < DD; ++k)
        acc = fmaf(pm[g][k], dw[k * DD + c], acc);
    float z = fmaxf(acc + db[c], 0.f);
    zs[g][c] = z * muw[c];
    __syncthreads();
    if (c == 0) {
        float s = 0.f;
        for (int k = 0; k < DD; ++k) s += zs[g][k];
        out[g] = s + mub[0];
    }
}

// ---------------- host ----------------

extern "C" void kernel_launch(void* const* d_in, const int* in_sizes, int n_in,
                              void* d_out, int out_size, void* d_ws, size_t ws_size,
                              hipStream_t stream) {
    const float* x      = (const float*)d_in[0];
    const int*   ei     = (const int*)d_in[1];
    const int*   batch  = (const int*)d_in[2];
    const float* W_rel  = (const float*)d_in[3];
    const float* b_rel  = (const float*)d_in[4];
    const float* W_root = (const float*)d_in[5];
    const float* gamma  = (const float*)d_in[6];
    const float* beta   = (const float*)d_in[7];
    const float* dw     = (const float*)d_in[8];
    const float* db     = (const float*)d_in[9];
    const float* muw    = (const float*)d_in[10];
    const float* mub    = (const float*)d_in[11];
    float* out = (float*)d_out;

    char* w = (char*)d_ws;
    auto alloc = [&](size_t bytes) {
        char* p = w;
        w += (bytes + 255) & ~(size_t)255;
        return p;
    };
    int*    off     = (int*)alloc((size_t)(NN + 1) * 4);
    int*    csr     = (int*)alloc((size_t)NE * 4);
    float*  aggb    = (float*)alloc((size_t)NN * DD * 4);  // doubles as partition scratch
    unsigned short* hbA = (unsigned short*)alloc((size_t)NN * DD * 2);
    unsigned short* hbB = (unsigned short*)alloc((size_t)NN * DD * 2);
    float*  stats   = (float*)alloc(2 * DD * 4);
    float*  st      = (float*)alloc(2 * DD * 4);
    float*  pooled  = (float*)alloc(NG * DD * 4);
    float*  counts  = (float*)alloc(NG * 4);
    int*    bincur  = (int*)alloc(256 * 4);
    int*    binbase = (int*)alloc(256 * 4);
    __bf16* wbuf    = (__bf16*)alloc((size_t)NLAYERS * 2 * 2 * DD * DD * 2);

    const int* src = ei;
    const int* dst = ei + NE;
    int2* scratch = (int2*)aggb;  // NBIN*BINCAP*8 = 16.06 MB <= 25.6 MB

    hipMemsetAsync(bincur, 0, 256 * 4, stream);
    hipMemsetAsync(stats, 0, 2 * DD * 4, stream);
    k_part<<<(NE + EPB - 1) / EPB, 1024, 0, stream>>>(src, dst, bincur, scratch);
    k_binscan<<<1, 256, 0, stream>>>(bincur, binbase, off);
    k_csr<<<NBIN, 1024, 0, stream>>>(bincur, binbase, scratch, off, csr);
    k_init_st<<<1, 256, 0, stream>>>(st);
    k_wprep<<<96, 256, 0, stream>>>(W_rel, W_root, wbuf);
    k_xtobf<<<(NN * DD / 8 + 255) / 256, 256, 0, stream>>>(x, hbA);

    const unsigned short* hcur = hbA;
    unsigned short* bufs[2] = {hbB, hbA};
    for (int i = 0; i < NLAYERS; ++i) {
        unsigned short* hnext = bufs[i & 1];
        k_agg<<<(NN * 64 + 255) / 256, 256, 0, stream>>>(hcur, off, csr, st, aggb);
        k_gemm<<<(NN + 63) / 64, 256, 0, stream>>>(
            aggb, hcur, st,
            wbuf + (size_t)(i * 2 + 0) * 32768,
            wbuf + (size_t)(i * 2 + 1) * 32768,
            b_rel + (size_t)i * DD, hnext, stats);
        k_bn<<<1, 128, 0, stream>>>(stats, gamma + (size_t)i * DD, beta + (size_t)i * DD, st);
        hcur = hnext;
    }
    hipMemsetAsync(pooled, 0, (size_t)NG * DD * 4, stream);
    hipMemsetAsync(counts, 0, (size_t)NG * 4, stream);
    k_pool<<<POOL_BLOCKS, 256, 0, stream>>>(hcur, batch, pooled, counts);
    k_head<<<1, 1024, 0, stream>>>(pooled, counts, st, dw, db, muw, mub, out);
}